// Round 7
// baseline (124.666 us; speedup 1.0000x reference)
//
#include <hip/hip_runtime.h>

// CenterLoss: loss = sum_i ||pred_i - centers[t_i]||^2 + BATCH*(NUM_CLASSES-1)*1e-12.
// (clamp [1e-12,1e12] provably inert for N(0,1) data: dist ~ 2048 +- ~90.)
// pred: [16384,1024] f32, centers: [10000,1024] f32, target: [16384] int.
//
// R7: gains R1->R6 tracked rows/wave (2->4->8 rows: 42->37->~29 us) => per-wave
// prologue (target load -> center addr -> first loads, ~1800 serial cyc) and
// per-block fixed cost are the limiters, not in-flight bytes. So: 16 rows/wave,
// 256 blocks (half the blocks, 2x prologue amortization), 3-deep register
// pipeline (prefetch 2 rows ahead; consume waits only on loads 2 rows old).
// Nontemporal hints dropped (R1 vs R4: no measurable effect).

constexpr int BATCH = 16384;
constexpr int FEAT = 1024;
constexpr int NUM_CLASSES = 10000;
constexpr int ROWS_PER_WAVE = 16;
constexpr int NBLOCKS = BATCH / (4 * ROWS_PER_WAVE);  // 256 blocks, 4 waves each

typedef float vf4 __attribute__((ext_vector_type(4)));

__global__ __launch_bounds__(256) void cl_main(const float* __restrict__ pred,
                                               const float* __restrict__ centers,
                                               const int* __restrict__ target,
                                               float* __restrict__ partials) {
    const int lane  = (int)(threadIdx.x & 63u);
    const int wave  = (int)(threadIdx.x >> 6);
    const int gwave = (int)blockIdx.x * 4 + wave;          // 1024 waves
    const int row0  = gwave * ROWS_PER_WAVE;

    // all 16 targets up front (contiguous -> compiler merges to dwordx4 loads)
    int t[ROWS_PER_WAVE];
#pragma unroll
    for (int k = 0; k < ROWS_PER_WAVE; ++k) t[k] = target[row0 + k];

    // 3-deep register pipeline: 8 loads (4 pred + 4 center vf4) per row,
    // 16 B/lane coalesced; 2 rows (16 KB/wave) in flight while computing.
    vf4 pa[3][4], ca[3][4];

    auto issue = [&](int k, int buf) {
        const vf4* p = reinterpret_cast<const vf4*>(pred    + (size_t)(row0 + k) * FEAT) + lane;
        const vf4* c = reinterpret_cast<const vf4*>(centers + (size_t)t[k]       * FEAT) + lane;
#pragma unroll
        for (int j = 0; j < 4; ++j) {
            pa[buf][j] = p[64 * j];
            ca[buf][j] = c[64 * j];
        }
    };

    issue(0, 0);   // prologue: rows 0 and 1 in flight before first consume
    issue(1, 1);

    float s0 = 0.0f, s1 = 0.0f;   // 2 accumulators: halve FMA dep-chain
#pragma unroll
    for (int k = 0; k < ROWS_PER_WAVE; ++k) {
        const int cur = k % 3;
        if (k + 2 < ROWS_PER_WAVE) issue(k + 2, (k + 2) % 3);  // prefetch 2 ahead
#pragma unroll
        for (int j = 0; j < 4; ++j) {
            const vf4 d = pa[cur][j] - ca[cur][j];
            s0 = fmaf(d.x, d.x, s0);
            s1 = fmaf(d.y, d.y, s1);
            s0 = fmaf(d.z, d.z, s0);
            s1 = fmaf(d.w, d.w, s1);
        }
    }
    float s = s0 + s1;

    // one reduction per block: wave butterfly -> LDS -> thread 0 -> plain store
#pragma unroll
    for (int off = 32; off > 0; off >>= 1)
        s += __shfl_xor(s, off, 64);

    __shared__ float red[4];
    if (lane == 0) red[wave] = s;
    __syncthreads();
    if (threadIdx.x == 0)
        partials[blockIdx.x] = red[0] + red[1] + red[2] + red[3];  // no atomics
}

__global__ __launch_bounds__(256) void cl_finalize(const float* __restrict__ partials,
                                                   float* __restrict__ out) {
    // 256 partials, one per thread (all written by cl_main before this launch)
    float s = partials[threadIdx.x];

#pragma unroll
    for (int off = 32; off > 0; off >>= 1)
        s += __shfl_xor(s, off, 64);

    __shared__ float red[4];
    if ((threadIdx.x & 63u) == 0) red[threadIdx.x >> 6] = s;
    __syncthreads();
    if (threadIdx.x == 0) {
        const float masked_const = (float)((double)BATCH * (double)(NUM_CLASSES - 1) * 1e-12);
        out[0] = red[0] + red[1] + red[2] + red[3] + masked_const;
    }
}

extern "C" void kernel_launch(void* const* d_in, const int* in_sizes, int n_in,
                              void* d_out, int out_size, void* d_ws, size_t ws_size,
                              hipStream_t stream) {
    const float* pred    = (const float*)d_in[0];
    const float* centers = (const float*)d_in[1];
    const int*   target  = (const int*)d_in[2];
    float*       out     = (float*)d_out;
    float*       partials = (float*)d_ws;   // 256 floats, fully written before read

    cl_main<<<NBLOCKS, 256, 0, stream>>>(pred, centers, target, partials);
    cl_finalize<<<1, 256, 0, stream>>>(partials, out);
}

// Round 9
// 122.751 us; speedup vs baseline: 1.0156x; 1.0156x over previous
//
#include <hip/hip_runtime.h>

// CenterLoss: loss = sum_i ||pred_i - centers[t_i]||^2 + BATCH*(NUM_CLASSES-1)*1e-12.
// (clamp [1e-12,1e12] provably inert for N(0,1) data: dist ~ 2048 +- ~90.)
// pred: [16384,1024] f32, centers: [10000,1024] f32, target: [16384] int.
//
// FINAL (revert to R6, best passing @124.58us): 512 blocks x 4 waves x
// 8 rows/wave, register double-buffer prefetch, per-block partials to d_ws
// (no same-address atomics), tiny finalize kernel folds the masked constant.
// Explored & saturated: load concurrency (R4), 2/3-deep pipelines (R5/R7),
// rows/wave 2->16 (R1..R7, saturates at 8), block count 2048->256 (no effect
// past R6), cooperative fused finalize (R8: silently fails under harness).
// Main loop delivers 128 MB in ~27us = 4.7 TB/s mixed-read ceiling.

constexpr int BATCH = 16384;
constexpr int FEAT = 1024;
constexpr int NUM_CLASSES = 10000;
constexpr int ROWS_PER_WAVE = 8;
constexpr int NBLOCKS = BATCH / (4 * ROWS_PER_WAVE);  // 512 blocks, 2/CU

typedef float vf4 __attribute__((ext_vector_type(4)));

__global__ __launch_bounds__(256) void cl_main(const float* __restrict__ pred,
                                               const float* __restrict__ centers,
                                               const int* __restrict__ target,
                                               float* __restrict__ partials) {
    const int lane  = (int)(threadIdx.x & 63u);
    const int wave  = (int)(threadIdx.x >> 6);
    const int gwave = (int)blockIdx.x * 4 + wave;          // 2048 waves
    const int row0  = gwave * ROWS_PER_WAVE;

    // all 8 targets up front (wave-uniform, contiguous -> scalar loads)
    int t[ROWS_PER_WAVE];
#pragma unroll
    for (int k = 0; k < ROWS_PER_WAVE; ++k) t[k] = target[row0 + k];

    // register double-buffer: 8 loads (4 pred + 4 center vf4) per row, 16 B/lane
    vf4 pa[2][4], ca[2][4];

    auto issue = [&](int k, int buf) {
        const vf4* p = reinterpret_cast<const vf4*>(pred    + (size_t)(row0 + k) * FEAT) + lane;
        const vf4* c = reinterpret_cast<const vf4*>(centers + (size_t)t[k]       * FEAT) + lane;
#pragma unroll
        for (int j = 0; j < 4; ++j) {
            pa[buf][j] = __builtin_nontemporal_load(&p[64 * j]);  // pred: streamed once
            ca[buf][j] = c[64 * j];                               // centers: cacheable
        }
    };

    issue(0, 0);  // prologue

    float s0 = 0.0f, s1 = 0.0f;   // 2 accumulators: halve FMA dep-chain
#pragma unroll
    for (int k = 0; k < ROWS_PER_WAVE; ++k) {
        const int cur = k & 1;
        if (k + 1 < ROWS_PER_WAVE) issue(k + 1, (k + 1) & 1);  // prefetch next row
#pragma unroll
        for (int j = 0; j < 4; ++j) {
            const vf4 d = pa[cur][j] - ca[cur][j];
            s0 = fmaf(d.x, d.x, s0);
            s1 = fmaf(d.y, d.y, s1);
            s0 = fmaf(d.z, d.z, s0);
            s1 = fmaf(d.w, d.w, s1);
        }
    }
    float s = s0 + s1;

    // one reduction per block: wave butterfly -> LDS -> thread 0 -> plain store
#pragma unroll
    for (int off = 32; off > 0; off >>= 1)
        s += __shfl_xor(s, off, 64);

    __shared__ float red[4];
    if (lane == 0) red[wave] = s;
    __syncthreads();
    if (threadIdx.x == 0)
        partials[blockIdx.x] = red[0] + red[1] + red[2] + red[3];  // no atomics
}

__global__ __launch_bounds__(256) void cl_finalize(const float* __restrict__ partials,
                                                   float* __restrict__ out) {
    // 512 partials: 2 per thread (all were written by cl_main; d_ws poison untouched)
    float s = partials[threadIdx.x] + partials[threadIdx.x + 256];

#pragma unroll
    for (int off = 32; off > 0; off >>= 1)
        s += __shfl_xor(s, off, 64);

    __shared__ float red[4];
    if ((threadIdx.x & 63u) == 0) red[threadIdx.x >> 6] = s;
    __syncthreads();
    if (threadIdx.x == 0) {
        const float masked_const = (float)((double)BATCH * (double)(NUM_CLASSES - 1) * 1e-12);
        out[0] = red[0] + red[1] + red[2] + red[3] + masked_const;
    }
}

extern "C" void kernel_launch(void* const* d_in, const int* in_sizes, int n_in,
                              void* d_out, int out_size, void* d_ws, size_t ws_size,
                              hipStream_t stream) {
    const float* pred    = (const float*)d_in[0];
    const float* centers = (const float*)d_in[1];
    const int*   target  = (const int*)d_in[2];
    float*       out     = (float*)d_out;
    float*       partials = (float*)d_ws;   // 512 floats, fully written before read

    cl_main<<<NBLOCKS, 256, 0, stream>>>(pred, centers, target, partials);
    cl_finalize<<<1, 256, 0, stream>>>(partials, out);
}